// Round 5
// baseline (504.343 us; speedup 1.0000x reference)
//
#include <hip/hip_runtime.h>
#include <hip/hip_bf16.h>
#include <hip/hip_cooperative_groups.h>

namespace cg = cooperative_groups;

#define EPSF 1e-5f

typedef int v4i __attribute__((ext_vector_type(4)));
typedef short v8s __attribute__((ext_vector_type(8)));

static constexpr int BB = 4, TT = 1024, DD = 2048, HH = 8192;
static constexpr int MROWS = BB * TT;                   // 4096
static constexpr long long WCOUNT = (long long)DD * HH; // 2^24 per weight

// ---------------------------------------------------------------- helpers

__device__ __forceinline__ void async_copy16(const void* g, void* l) {
  __builtin_amdgcn_global_load_lds(
      (const __attribute__((address_space(1))) unsigned int*)g,
      (__attribute__((address_space(3))) unsigned int*)l,
      16, 0, 0);
}

__device__ __forceinline__ int pack4(float a, float b, float c, float d,
                                     float scale, float lo, float hi) {
  int ia = (int)fminf(fmaxf(rintf(a * scale), lo), hi);
  int ib = (int)fminf(fmaxf(rintf(b * scale), lo), hi);
  int ic = (int)fminf(fmaxf(rintf(c * scale), lo), hi);
  int id = (int)fminf(fmaxf(rintf(d * scale), lo), hi);
  return (ia & 0xff) | ((ib & 0xff) << 8) | ((ic & 0xff) << 16) | ((id & 0xff) << 24);
}

__device__ __forceinline__ float abs4(float4 v) {
  return fmaxf(fmaxf(fabsf(v.x), fabsf(v.y)), fmaxf(fabsf(v.z), fabsf(v.w)));
}

__device__ __forceinline__ int blockMaxI256(int v) {
  #pragma unroll
  for (int off = 32; off; off >>= 1) v = max(v, __shfl_down(v, off, 64));
  __shared__ int sm[4];
  int lane = threadIdx.x & 63, wv = threadIdx.x >> 6;
  if (lane == 0) sm[wv] = v;
  __syncthreads();
  return max(max(sm[0], sm[1]), max(sm[2], sm[3]));
}

// XCD-aware tile swizzle: id%8 class (heuristic XCD) owns a contiguous patch.
__device__ __forceinline__ void swizzle_tiles(int& mt, int& nt) {
  int Mt = gridDim.y, Nt = gridDim.x;
  int id = blockIdx.y * Nt + blockIdx.x;
  int c = id & 7, k = id >> 3;
  int pm = (Mt >= Nt) ? 4 : 2;
  int PM = Mt / pm, PN = Nt / (8 / pm);
  int pr = c % pm, pc = c / pm;
  mt = pr * PM + (k % PM);
  nt = pc * PN + (k / PM);
}

// ---------------------------------------------------------------- fused pre-pass
// One cooperative dispatch, 1024 blocks x 256. MLP fix (R4 post-mortem):
// explicit 8-deep float4 load batches (128 B in flight/thread) — the
// compiler does NOT software-pipeline grid-stride reduce loops (VGPR=24,
// 1.27 TB/s observed in R4).

__global__ __launch_bounds__(256, 4) void fused_pre_kernel(
    const float* __restrict__ w1, const float* __restrict__ w2,
    const float* __restrict__ x, float* __restrict__ meanw,
    float* __restrict__ partials, signed char* __restrict__ w1q,
    signed char* __restrict__ w2q, signed char* __restrict__ xq,
    float* __restrict__ a1) {
  const int t = threadIdx.x, bid = blockIdx.x;
  const int lane = t & 63, wv = t >> 6;
  const int tid = bid * 256 + t;          // 0..262143
  constexpr int TH = 1024 * 256;          // total threads
  constexpr int ITER = (int)(WCOUNT / 4 / TH); // 16 float4 per thread per w

  const float4* w14 = (const float4*)w1;
  const float4* w24 = (const float4*)w2;

  // ---- phase A: |w| partial sums, 8 loads in flight
  float s1 = 0.f, s2 = 0.f;
  #pragma unroll
  for (int b = 0; b < ITER; b += 8) {
    float4 u[8];
    #pragma unroll
    for (int k = 0; k < 8; k++) u[k] = w14[(long long)(b + k) * TH + tid];
    #pragma unroll
    for (int k = 0; k < 8; k++)
      s1 += fabsf(u[k].x) + fabsf(u[k].y) + fabsf(u[k].z) + fabsf(u[k].w);
  }
  #pragma unroll
  for (int b = 0; b < ITER; b += 8) {
    float4 u[8];
    #pragma unroll
    for (int k = 0; k < 8; k++) u[k] = w24[(long long)(b + k) * TH + tid];
    #pragma unroll
    for (int k = 0; k < 8; k++)
      s2 += fabsf(u[k].x) + fabsf(u[k].y) + fabsf(u[k].z) + fabsf(u[k].w);
  }
  #pragma unroll
  for (int off = 32; off; off >>= 1) {
    s1 += __shfl_down(s1, off, 64);
    s2 += __shfl_down(s2, off, 64);
  }
  __shared__ float sms[8];
  if (lane == 0) { sms[wv] = s1; sms[wv + 4] = s2; }
  __syncthreads();
  if (t == 0) {
    partials[bid] = sms[0] + sms[1] + sms[2] + sms[3];
    partials[1024 + bid] = sms[4] + sms[5] + sms[6] + sms[7];
  }

  // ---- phase A: act quant, one wave = one row (no block barriers)
  {
    int row = bid * 4 + wv;
    const float4* xr = (const float4*)(x + (size_t)row * DD); // 512 float4
    float4 v[8];
    #pragma unroll
    for (int j = 0; j < 8; j++) v[j] = xr[lane + j * 64];
    float m = 0.f;
    #pragma unroll
    for (int j = 0; j < 8; j++) m = fmaxf(m, abs4(v[j]));
    #pragma unroll
    for (int off = 32; off; off >>= 1) m = fmaxf(m, __shfl_down(m, off, 64));
    m = __shfl(m, 0, 64);
    float am = fmaxf(m, EPSF);
    float scale = 127.0f / am;
    int* outp = (int*)(xq + (size_t)row * DD);
    #pragma unroll
    for (int j = 0; j < 8; j++)
      outp[lane + j * 64] = pack4(v[j].x, v[j].y, v[j].z, v[j].w, scale, -128.f, 127.f);
    if (lane == 0) a1[row] = am / 127.0f;
  }

  cg::this_grid().sync();

  // ---- phase B: deterministic mean (identical tree in every block)
  double d1 = (double)partials[t] + (double)partials[t + 256] +
              (double)partials[t + 512] + (double)partials[t + 768];
  double d2 = (double)partials[1024 + t] + (double)partials[1280 + t] +
              (double)partials[1536 + t] + (double)partials[1792 + t];
  #pragma unroll
  for (int off = 32; off; off >>= 1) {
    d1 += __shfl_down(d1, off, 64);
    d2 += __shfl_down(d2, off, 64);
  }
  __shared__ double smd[8];
  if (lane == 0) { smd[wv] = d1; smd[wv + 4] = d2; }
  __syncthreads();
  double sum1 = smd[0] + smd[1] + smd[2] + smd[3];
  double sum2 = smd[4] + smd[5] + smd[6] + smd[7];
  float mean1 = fmaxf((float)(sum1 * (1.0 / (double)WCOUNT)), EPSF);
  float mean2 = fmaxf((float)(sum2 * (1.0 / (double)WCOUNT)), EPSF);
  if (bid == 0 && t == 0) { meanw[0] = mean1; meanw[1] = mean2; }

  // ---- phase B: ternary quant, batched (second w read is L3-resident, R4)
  float sc1 = 1.0f / mean1, sc2 = 1.0f / mean2;
  int* q14 = (int*)w1q;
  int* q24 = (int*)w2q;
  #pragma unroll
  for (int b = 0; b < ITER; b += 8) {
    float4 u[8];
    #pragma unroll
    for (int k = 0; k < 8; k++) u[k] = w14[(long long)(b + k) * TH + tid];
    #pragma unroll
    for (int k = 0; k < 8; k++)
      q14[(long long)(b + k) * TH + tid] =
          pack4(u[k].x, u[k].y, u[k].z, u[k].w, sc1, -1.f, 1.f);
  }
  #pragma unroll
  for (int b = 0; b < ITER; b += 8) {
    float4 u[8];
    #pragma unroll
    for (int k = 0; k < 8; k++) u[k] = w24[(long long)(b + k) * TH + tid];
    #pragma unroll
    for (int k = 0; k < 8; k++)
      q24[(long long)(b + k) * TH + tid] =
          pack4(u[k].x, u[k].y, u[k].z, u[k].w, sc2, -1.f, 1.f);
  }
}

// ---------------------------------------------------------------- fallback path
// (non-cooperative; same batched-load structure)

__global__ __launch_bounds__(256) void abs_sum_kernel(
    const float* __restrict__ w1, const float* __restrict__ w2,
    double* __restrict__ sums) {
  const float4* w4 = (const float4*)(blockIdx.y ? w2 : w1);
  const int tid = blockIdx.x * 256 + threadIdx.x;
  constexpr int TH = 1024 * 256;
  constexpr int ITER = (int)(WCOUNT / 4 / TH);
  float s = 0.f;
  #pragma unroll
  for (int b = 0; b < ITER; b += 8) {
    float4 u[8];
    #pragma unroll
    for (int k = 0; k < 8; k++) u[k] = w4[(long long)(b + k) * TH + tid];
    #pragma unroll
    for (int k = 0; k < 8; k++)
      s += fabsf(u[k].x) + fabsf(u[k].y) + fabsf(u[k].z) + fabsf(u[k].w);
  }
  #pragma unroll
  for (int off = 32; off; off >>= 1) s += __shfl_down(s, off, 64);
  __shared__ float sm[4];
  int lane = threadIdx.x & 63, wv = threadIdx.x >> 6;
  if (lane == 0) sm[wv] = s;
  __syncthreads();
  if (threadIdx.x == 0)
    atomicAdd(&sums[blockIdx.y], (double)(sm[0] + sm[1] + sm[2] + sm[3]));
}

__global__ __launch_bounds__(256) void quant_w_kernel(
    const float* __restrict__ w1, const float* __restrict__ w2,
    const double* __restrict__ sums, float* __restrict__ meanw,
    signed char* __restrict__ q1, signed char* __restrict__ q2) {
  const float4* w4 = (const float4*)(blockIdx.y ? w2 : w1);
  int* q4 = (int*)(blockIdx.y ? q2 : q1);
  float mean = fmaxf((float)(sums[blockIdx.y] * (1.0 / (double)WCOUNT)), EPSF);
  if (blockIdx.x == 0 && threadIdx.x == 0) meanw[blockIdx.y] = mean;
  float scale = 1.0f / mean;
  const int tid = blockIdx.x * 256 + threadIdx.x;
  constexpr int TH = 1024 * 256;
  constexpr int ITER = (int)(WCOUNT / 4 / TH);
  #pragma unroll
  for (int b = 0; b < ITER; b += 8) {
    float4 u[8];
    #pragma unroll
    for (int k = 0; k < 8; k++) u[k] = w4[(long long)(b + k) * TH + tid];
    #pragma unroll
    for (int k = 0; k < 8; k++)
      q4[(long long)(b + k) * TH + tid] =
          pack4(u[k].x, u[k].y, u[k].z, u[k].w, scale, -1.f, 1.f);
  }
}

__global__ __launch_bounds__(256) void quant_x_kernel(
    const float* __restrict__ x, signed char* __restrict__ xq,
    float* __restrict__ ascale) {
  int lane = threadIdx.x & 63, wv = threadIdx.x >> 6;
  int row = blockIdx.x * 4 + wv;
  const float4* xr = (const float4*)(x + (size_t)row * DD);
  float4 v[8];
  #pragma unroll
  for (int j = 0; j < 8; j++) v[j] = xr[lane + j * 64];
  float m = 0.f;
  #pragma unroll
  for (int j = 0; j < 8; j++) m = fmaxf(m, abs4(v[j]));
  #pragma unroll
  for (int off = 32; off; off >>= 1) m = fmaxf(m, __shfl_down(m, off, 64));
  m = __shfl(m, 0, 64);
  float am = fmaxf(m, EPSF);
  float scale = 127.0f / am;
  int* out = (int*)(xq + (size_t)row * DD);
  #pragma unroll
  for (int j = 0; j < 8; j++)
    out[lane + j * 64] = pack4(v[j].x, v[j].y, v[j].z, v[j].w, scale, -128.f, 127.f);
  if (lane == 0) ascale[row] = am / 127.0f;
}

// ---------------------------------------------------------------- act quant h (int16 in)

__global__ __launch_bounds__(256) void quant_h_kernel(
    const short* __restrict__ h, signed char* __restrict__ hq,
    float* __restrict__ a2, const float* __restrict__ a1,
    const float* __restrict__ meanw) {
  int row = blockIdx.x;
  int t = threadIdx.x;
  const v8s* hr = (const v8s*)(h + (size_t)row * HH);
  v8s v[4];
  #pragma unroll
  for (int i = 0; i < 4; i++) v[i] = hr[t + i * 256];
  int mx = 0;
  #pragma unroll
  for (int i = 0; i < 4; i++)
    #pragma unroll
    for (int j = 0; j < 8; j++) mx = max(mx, (int)v[i][j]);
  int bmx = blockMaxI256(mx);
  float f = a1[row] * meanw[0];      // per-row dequant factor (exact ref path)
  float maxh = (float)bmx * f;       // == max_j fl(r_j*f): fl monotone, f>=0
  float am = fmaxf(maxh, EPSF);
  float scale = 127.0f / am;
  int* out = (int*)(hq + (size_t)row * HH);
  #pragma unroll
  for (int i = 0; i < 4; i++) {
    out[(t + i * 256) * 2] =
        pack4((float)v[i][0] * f, (float)v[i][1] * f, (float)v[i][2] * f,
              (float)v[i][3] * f, scale, -128.f, 127.f);
    out[(t + i * 256) * 2 + 1] =
        pack4((float)v[i][4] * f, (float)v[i][5] * f, (float)v[i][6] * f,
              (float)v[i][7] * f, scale, -128.f, 127.f);
  }
  if (t == 0) a2[row] = am / 127.0f;
}

// ---------------------------------------------------------------- int8 GEMM (round-2 structure, frozen)
// C[M][N] = sum_k A[M][K]*B[N][K], both operands LDS-staged via
// global_load_lds w16, XOR 16B-chunk swizzle (0 conflicts, verified R1/R2).
// 128x128 tile, 4 waves 2x2, wave 64x64 via 4x4 mfma_i32_16x16x64_i8.
// MODE 1: relu -> int16 store (exact). MODE 0: scaled fp32 store.

template <int MODE, int BK>
__global__ __launch_bounds__(256) void gemm_i8_kernel(
    const signed char* __restrict__ A, const signed char* __restrict__ B,
    void* __restrict__ Cout, const float* __restrict__ ascale,
    const float* __restrict__ wmean_p, int M, int N, int K) {
  constexpr int CH = BK / 16;
  constexpr int SEGROWS = 1024 / BK;
  constexpr int SPW = BK / 32;
  __shared__ signed char As[128 * BK];
  __shared__ signed char Bs[128 * BK];

  const int t = threadIdx.x;
  const int lane = t & 63, wv = t >> 6;
  const int wm = wv >> 1, wn = wv & 1;
  int mt, nt;
  swizzle_tiles(mt, nt);
  const int m0 = mt * 128, n0 = nt * 128;
  const int q = lane >> 4;

  const signed char* aSrc[SPW];
  const signed char* bSrc[SPW];
  #pragma unroll
  for (int i = 0; i < SPW; i++) {
    int seg = wv * SPW + i;
    int r = seg * SEGROWS + lane / CH;
    int c = (lane % CH) ^ (r & (CH - 1));
    aSrc[i] = A + (size_t)(m0 + r) * K + c * 16;
    bSrc[i] = B + (size_t)(n0 + r) * K + c * 16;
  }

  v4i acc[4][4];
  #pragma unroll
  for (int i = 0; i < 4; i++)
    #pragma unroll
    for (int j = 0; j < 4; j++) {
      v4i z = {0, 0, 0, 0};
      acc[i][j] = z;
    }

  int rowA[4], rowB[4];
  #pragma unroll
  for (int i = 0; i < 4; i++) {
    rowA[i] = wm * 64 + i * 16 + (lane & 15);
    rowB[i] = wn * 64 + i * 16 + (lane & 15);
  }

  for (int k0 = 0; k0 < K; k0 += BK) {
    #pragma unroll
    for (int i = 0; i < SPW; i++) {
      async_copy16(aSrc[i] + k0, &As[(wv * SPW + i) * 1024]);
      async_copy16(bSrc[i] + k0, &Bs[(wv * SPW + i) * 1024]);
    }
    __syncthreads();
    #pragma unroll
    for (int kc = 0; kc < CH / 4; kc++) {
      v4i af[4], bf[4];
      #pragma unroll
      for (int i = 0; i < 4; i++) {
        int ca = (kc * 4 + q) ^ (rowA[i] & (CH - 1));
        af[i] = *(const v4i*)(As + rowA[i] * BK + ca * 16);
        int cb = (kc * 4 + q) ^ (rowB[i] & (CH - 1));
        bf[i] = *(const v4i*)(Bs + rowB[i] * BK + cb * 16);
      }
      #pragma unroll
      for (int i = 0; i < 4; i++)
        #pragma unroll
        for (int j = 0; j < 4; j++)
          acc[i][j] = __builtin_amdgcn_mfma_i32_16x16x64_i8(af[i], bf[j], acc[i][j], 0, 0, 0);
    }
    __syncthreads();
  }

  if constexpr (MODE == 1) {
    short* C = (short*)Cout;
    #pragma unroll
    for (int i = 0; i < 4; i++) {
      int mBase = m0 + wm * 64 + i * 16 + q * 4;
      #pragma unroll
      for (int e = 0; e < 4; e++) {
        #pragma unroll
        for (int j = 0; j < 4; j++) {
          int n = n0 + wn * 64 + j * 16 + (lane & 15);
          int r = acc[i][j][e];
          r = r < 0 ? 0 : (r > 32767 ? 32767 : r);
          C[(size_t)(mBase + e) * N + n] = (short)r;
        }
      }
    }
  } else {
    float* C = (float*)Cout;
    float wmean = wmean_p[0];
    #pragma unroll
    for (int i = 0; i < 4; i++) {
      int mBase = m0 + wm * 64 + i * 16 + q * 4;
      #pragma unroll
      for (int e = 0; e < 4; e++) {
        float f = ascale[mBase + e] * wmean;
        #pragma unroll
        for (int j = 0; j < 4; j++) {
          int n = n0 + wn * 64 + j * 16 + (lane & 15);
          C[(size_t)(mBase + e) * N + n] = (float)acc[i][j][e] * f;
        }
      }
    }
  }
}

// ---------------------------------------------------------------- launch

extern "C" void kernel_launch(void* const* d_in, const int* in_sizes, int n_in,
                              void* d_out, int out_size, void* d_ws, size_t ws_size,
                              hipStream_t stream) {
  const float* x  = (const float*)d_in[0];
  const float* w1 = (const float*)d_in[1];
  const float* w2 = (const float*)d_in[2];
  float* out = (float*)d_out;

  char* ws = (char*)d_ws;
  float* meanw = (float*)ws;                                // 2 f32
  double* sums = (double*)(ws + 128);                       // 16 B (fallback)
  float* partials = (float*)(ws + 256);                     // 2048 f32
  float* a1 = (float*)(ws + 16384);                         // 4096 f32
  float* a2 = (float*)(ws + 32768);                         // 4096 f32
  signed char* w1q = (signed char*)(ws + 65536);            // 16 MB
  signed char* w2q = w1q + (size_t)WCOUNT;                  // 16 MB
  signed char* xq  = w2q + (size_t)WCOUNT;                  // 8 MB
  signed char* hq  = xq + (size_t)MROWS * DD;               // 32 MB
  short* h16 = (short*)(hq + (size_t)MROWS * HH);           // 64 MB int16

  {
    const float* aw1 = w1; const float* aw2 = w2; const float* ax = x;
    float* ameanw = meanw; float* apart = partials;
    signed char* aq1 = w1q; signed char* aq2 = w2q; signed char* axq = xq;
    float* aa1 = a1;
    void* args[] = {&aw1, &aw2, &ax, &ameanw, &apart, &aq1, &aq2, &axq, &aa1};
    hipError_t ce = hipLaunchCooperativeKernel(
        (const void*)fused_pre_kernel, dim3(1024), dim3(256), args, 0, stream);
    if (ce != hipSuccess) {
      hipMemsetAsync(sums, 0, 16, stream);
      abs_sum_kernel<<<dim3(1024, 2), 256, 0, stream>>>(w1, w2, sums);
      quant_w_kernel<<<dim3(1024, 2), 256, 0, stream>>>(w1, w2, sums, meanw, w1q, w2q);
      quant_x_kernel<<<MROWS / 4, 256, 0, stream>>>(x, xq, a1);
    }
  }
  // GEMM1: M=4096, N=8192, K=2048 — BK=128, relu->int16
  gemm_i8_kernel<1, 128><<<dim3(HH / 128, MROWS / 128), 256, 0, stream>>>(
      xq, w1q, h16, nullptr, meanw, MROWS, HH, DD);
  quant_h_kernel<<<MROWS, 256, 0, stream>>>(h16, hq, a2, a1, meanw);
  // GEMM2: M=4096, N=2048, K=8192 — BK=256, scaled fp32
  gemm_i8_kernel<0, 256><<<dim3(DD / 128, MROWS / 128), 256, 0, stream>>>(
      hq, w2q, out, a2, &meanw[1], MROWS, DD, HH);
}

// Round 6
// 374.263 us; speedup vs baseline: 1.3476x; 1.3476x over previous
//
#include <hip/hip_runtime.h>
#include <hip/hip_bf16.h>

#define EPSF 1e-5f

typedef int v4i __attribute__((ext_vector_type(4)));
typedef short v8s __attribute__((ext_vector_type(8)));

static constexpr int BB = 4, TT = 1024, DD = 2048, HH = 8192;
static constexpr int MROWS = BB * TT;                   // 4096
static constexpr long long WCOUNT = (long long)DD * HH; // 2^24 per weight

// ---------------------------------------------------------------- helpers

__device__ __forceinline__ void async_copy16(const void* g, void* l) {
  __builtin_amdgcn_global_load_lds(
      (const __attribute__((address_space(1))) unsigned int*)g,
      (__attribute__((address_space(3))) unsigned int*)l,
      16, 0, 0);
}

__device__ __forceinline__ int pack4(float a, float b, float c, float d,
                                     float scale, float lo, float hi) {
  int ia = (int)fminf(fmaxf(rintf(a * scale), lo), hi);
  int ib = (int)fminf(fmaxf(rintf(b * scale), lo), hi);
  int ic = (int)fminf(fmaxf(rintf(c * scale), lo), hi);
  int id = (int)fminf(fmaxf(rintf(d * scale), lo), hi);
  return (ia & 0xff) | ((ib & 0xff) << 8) | ((ic & 0xff) << 16) | ((id & 0xff) << 24);
}

__device__ __forceinline__ float abs4(float4 v) {
  return fmaxf(fmaxf(fabsf(v.x), fabsf(v.y)), fmaxf(fabsf(v.z), fabsf(v.w)));
}

__device__ __forceinline__ int blockMaxI256(int v) {
  #pragma unroll
  for (int off = 32; off; off >>= 1) v = max(v, __shfl_down(v, off, 64));
  __shared__ int sm[4];
  int lane = threadIdx.x & 63, wv = threadIdx.x >> 6;
  if (lane == 0) sm[wv] = v;
  __syncthreads();
  return max(max(sm[0], sm[1]), max(sm[2], sm[3]));
}

// XCD-aware tile swizzle: id%8 class (heuristic XCD) owns a contiguous patch.
__device__ __forceinline__ void swizzle_tiles(int& mt, int& nt) {
  int Mt = gridDim.y, Nt = gridDim.x;
  int id = blockIdx.y * Nt + blockIdx.x;
  int c = id & 7, k = id >> 3;
  int pm = (Mt >= Nt) ? 4 : 2;
  int PM = Mt / pm, PN = Nt / (8 / pm);
  int pr = c % pm, pc = c / pm;
  mt = pr * PM + (k % PM);
  nt = pc * PN + (k / PM);
}

// ---------------------------------------------------------------- |w| partial sums
// 2048 blocks per weight; block owns ONE contiguous 32 KB extent (2048
// float4). No atomics: per-block partial -> partials[y*2048+bid].

__global__ __launch_bounds__(256) void abs_sum_kernel(
    const float* __restrict__ w1, const float* __restrict__ w2,
    float* __restrict__ partials) {
  const int y = blockIdx.y, bid = blockIdx.x, t = threadIdx.x;
  const int lane = t & 63, wv = t >> 6;
  const float4* w4 = (const float4*)(y ? w2 : w1);
  const long long base = (long long)bid * 2048;
  float4 u[8];
  #pragma unroll
  for (int k = 0; k < 8; k++) u[k] = w4[base + t + k * 256];
  float s = 0.f;
  #pragma unroll
  for (int k = 0; k < 8; k++)
    s += fabsf(u[k].x) + fabsf(u[k].y) + fabsf(u[k].z) + fabsf(u[k].w);
  #pragma unroll
  for (int off = 32; off; off >>= 1) s += __shfl_down(s, off, 64);
  __shared__ float sm[4];
  if (lane == 0) sm[wv] = s;
  __syncthreads();
  if (t == 0) partials[y * 2048 + bid] = sm[0] + sm[1] + sm[2] + sm[3];
}

// ---------------------------------------------------------------- ternary quant
// Every block re-reduces the 2048 partials with an IDENTICAL tree
// (deterministic, ~8KB L2-hit reads), then quantizes its 32 KB extent
// (L3-warm after abs_sum).

__global__ __launch_bounds__(256) void quant_w_kernel(
    const float* __restrict__ w1, const float* __restrict__ w2,
    const float* __restrict__ partials, float* __restrict__ meanw,
    signed char* __restrict__ q1, signed char* __restrict__ q2) {
  const int y = blockIdx.y, bid = blockIdx.x, t = threadIdx.x;
  const int lane = t & 63, wv = t >> 6;

  double d = 0.0;
  #pragma unroll
  for (int j = 0; j < 8; j++) d += (double)partials[y * 2048 + t + j * 256];
  #pragma unroll
  for (int off = 32; off; off >>= 1) d += __shfl_down(d, off, 64);
  __shared__ double smd[4];
  if (lane == 0) smd[wv] = d;
  __syncthreads();
  double sum = smd[0] + smd[1] + smd[2] + smd[3];
  float mean = fmaxf((float)(sum * (1.0 / (double)WCOUNT)), EPSF);
  if (bid == 0 && t == 0) meanw[y] = mean;
  float sc = 1.0f / mean;

  const float4* w4 = (const float4*)(y ? w2 : w1);
  int* q4 = (int*)(y ? q2 : q1);
  const long long base = (long long)bid * 2048;
  float4 u[8];
  #pragma unroll
  for (int k = 0; k < 8; k++) u[k] = w4[base + t + k * 256];
  #pragma unroll
  for (int k = 0; k < 8; k++)
    q4[base + t + k * 256] = pack4(u[k].x, u[k].y, u[k].z, u[k].w, sc, -1.f, 1.f);
}

// ---------------------------------------------------------------- act quant x (wave = row)

__global__ __launch_bounds__(256) void quant_x_kernel(
    const float* __restrict__ x, signed char* __restrict__ xq,
    float* __restrict__ ascale) {
  int lane = threadIdx.x & 63, wv = threadIdx.x >> 6;
  int row = blockIdx.x * 4 + wv;
  const float4* xr = (const float4*)(x + (size_t)row * DD);
  float4 v[8];
  #pragma unroll
  for (int j = 0; j < 8; j++) v[j] = xr[lane + j * 64];
  float m = 0.f;
  #pragma unroll
  for (int j = 0; j < 8; j++) m = fmaxf(m, abs4(v[j]));
  #pragma unroll
  for (int off = 32; off; off >>= 1) m = fmaxf(m, __shfl_down(m, off, 64));
  m = __shfl(m, 0, 64);
  float am = fmaxf(m, EPSF);
  float scale = 127.0f / am;
  int* out = (int*)(xq + (size_t)row * DD);
  #pragma unroll
  for (int j = 0; j < 8; j++)
    out[lane + j * 64] = pack4(v[j].x, v[j].y, v[j].z, v[j].w, scale, -128.f, 127.f);
  if (lane == 0) ascale[row] = am / 127.0f;
}

// ---------------------------------------------------------------- act quant h (int16 in)

__global__ __launch_bounds__(256) void quant_h_kernel(
    const short* __restrict__ h, signed char* __restrict__ hq,
    float* __restrict__ a2, const float* __restrict__ a1,
    const float* __restrict__ meanw) {
  int row = blockIdx.x;
  int t = threadIdx.x;
  const v8s* hr = (const v8s*)(h + (size_t)row * HH);
  v8s v[4];
  #pragma unroll
  for (int i = 0; i < 4; i++) v[i] = hr[t + i * 256];
  int mx = 0;
  #pragma unroll
  for (int i = 0; i < 4; i++)
    #pragma unroll
    for (int j = 0; j < 8; j++) mx = max(mx, (int)v[i][j]);
  int bmx = blockMaxI256(mx);
  float f = a1[row] * meanw[0];      // per-row dequant factor (exact ref path)
  float maxh = (float)bmx * f;       // == max_j fl(r_j*f): fl monotone, f>=0
  float am = fmaxf(maxh, EPSF);
  float scale = 127.0f / am;
  int* out = (int*)(hq + (size_t)row * HH);
  #pragma unroll
  for (int i = 0; i < 4; i++) {
    out[(t + i * 256) * 2] =
        pack4((float)v[i][0] * f, (float)v[i][1] * f, (float)v[i][2] * f,
              (float)v[i][3] * f, scale, -128.f, 127.f);
    out[(t + i * 256) * 2 + 1] =
        pack4((float)v[i][4] * f, (float)v[i][5] * f, (float)v[i][6] * f,
              (float)v[i][7] * f, scale, -128.f, 127.f);
  }
  if (t == 0) a2[row] = am / 127.0f;
}

// ---------------------------------------------------------------- int8 GEMM (round-2 structure, frozen)
// C[M][N] = sum_k A[M][K]*B[N][K], both operands LDS-staged via
// global_load_lds w16, XOR 16B-chunk swizzle (0 conflicts, verified R1/R2).
// 128x128 tile, 4 waves 2x2, wave 64x64 via 4x4 mfma_i32_16x16x64_i8.
// MODE 1: relu -> int16 store (exact). MODE 0: scaled fp32 store.

template <int MODE, int BK>
__global__ __launch_bounds__(256) void gemm_i8_kernel(
    const signed char* __restrict__ A, const signed char* __restrict__ B,
    void* __restrict__ Cout, const float* __restrict__ ascale,
    const float* __restrict__ wmean_p, int M, int N, int K) {
  constexpr int CH = BK / 16;
  constexpr int SEGROWS = 1024 / BK;
  constexpr int SPW = BK / 32;
  __shared__ signed char As[128 * BK];
  __shared__ signed char Bs[128 * BK];

  const int t = threadIdx.x;
  const int lane = t & 63, wv = t >> 6;
  const int wm = wv >> 1, wn = wv & 1;
  int mt, nt;
  swizzle_tiles(mt, nt);
  const int m0 = mt * 128, n0 = nt * 128;
  const int q = lane >> 4;

  const signed char* aSrc[SPW];
  const signed char* bSrc[SPW];
  #pragma unroll
  for (int i = 0; i < SPW; i++) {
    int seg = wv * SPW + i;
    int r = seg * SEGROWS + lane / CH;
    int c = (lane % CH) ^ (r & (CH - 1));
    aSrc[i] = A + (size_t)(m0 + r) * K + c * 16;
    bSrc[i] = B + (size_t)(n0 + r) * K + c * 16;
  }

  v4i acc[4][4];
  #pragma unroll
  for (int i = 0; i < 4; i++)
    #pragma unroll
    for (int j = 0; j < 4; j++) {
      v4i z = {0, 0, 0, 0};
      acc[i][j] = z;
    }

  int rowA[4], rowB[4];
  #pragma unroll
  for (int i = 0; i < 4; i++) {
    rowA[i] = wm * 64 + i * 16 + (lane & 15);
    rowB[i] = wn * 64 + i * 16 + (lane & 15);
  }

  for (int k0 = 0; k0 < K; k0 += BK) {
    #pragma unroll
    for (int i = 0; i < SPW; i++) {
      async_copy16(aSrc[i] + k0, &As[(wv * SPW + i) * 1024]);
      async_copy16(bSrc[i] + k0, &Bs[(wv * SPW + i) * 1024]);
    }
    __syncthreads();
    #pragma unroll
    for (int kc = 0; kc < CH / 4; kc++) {
      v4i af[4], bf[4];
      #pragma unroll
      for (int i = 0; i < 4; i++) {
        int ca = (kc * 4 + q) ^ (rowA[i] & (CH - 1));
        af[i] = *(const v4i*)(As + rowA[i] * BK + ca * 16);
        int cb = (kc * 4 + q) ^ (rowB[i] & (CH - 1));
        bf[i] = *(const v4i*)(Bs + rowB[i] * BK + cb * 16);
      }
      #pragma unroll
      for (int i = 0; i < 4; i++)
        #pragma unroll
        for (int j = 0; j < 4; j++)
          acc[i][j] = __builtin_amdgcn_mfma_i32_16x16x64_i8(af[i], bf[j], acc[i][j], 0, 0, 0);
    }
    __syncthreads();
  }

  if constexpr (MODE == 1) {
    short* C = (short*)Cout;
    #pragma unroll
    for (int i = 0; i < 4; i++) {
      int mBase = m0 + wm * 64 + i * 16 + q * 4;
      #pragma unroll
      for (int e = 0; e < 4; e++) {
        #pragma unroll
        for (int j = 0; j < 4; j++) {
          int n = n0 + wn * 64 + j * 16 + (lane & 15);
          int r = acc[i][j][e];
          r = r < 0 ? 0 : (r > 32767 ? 32767 : r);
          C[(size_t)(mBase + e) * N + n] = (short)r;
        }
      }
    }
  } else {
    float* C = (float*)Cout;
    float wmean = wmean_p[0];
    #pragma unroll
    for (int i = 0; i < 4; i++) {
      int mBase = m0 + wm * 64 + i * 16 + q * 4;
      #pragma unroll
      for (int e = 0; e < 4; e++) {
        float f = ascale[mBase + e] * wmean;
        #pragma unroll
        for (int j = 0; j < 4; j++) {
          int n = n0 + wn * 64 + j * 16 + (lane & 15);
          C[(size_t)(mBase + e) * N + n] = (float)acc[i][j][e] * f;
        }
      }
    }
  }
}

// ---------------------------------------------------------------- launch

extern "C" void kernel_launch(void* const* d_in, const int* in_sizes, int n_in,
                              void* d_out, int out_size, void* d_ws, size_t ws_size,
                              hipStream_t stream) {
  const float* x  = (const float*)d_in[0];
  const float* w1 = (const float*)d_in[1];
  const float* w2 = (const float*)d_in[2];
  float* out = (float*)d_out;

  char* ws = (char*)d_ws;
  float* meanw = (float*)ws;                                // 2 f32
  float* partials = (float*)(ws + 1024);                    // 4096 f32 (16 KB)
  float* a1 = (float*)(ws + 20480);                         // 4096 f32
  float* a2 = (float*)(ws + 40960);                         // 4096 f32
  signed char* w1q = (signed char*)(ws + 65536);            // 16 MB
  signed char* w2q = w1q + (size_t)WCOUNT;                  // 16 MB
  signed char* xq  = w2q + (size_t)WCOUNT;                  // 8 MB
  signed char* hq  = xq + (size_t)MROWS * DD;               // 32 MB
  short* h16 = (short*)(hq + (size_t)MROWS * HH);           // 64 MB int16

  abs_sum_kernel<<<dim3(2048, 2), 256, 0, stream>>>(w1, w2, partials);
  quant_w_kernel<<<dim3(2048, 2), 256, 0, stream>>>(w1, w2, partials, meanw, w1q, w2q);
  quant_x_kernel<<<MROWS / 4, 256, 0, stream>>>(x, xq, a1);
  // GEMM1: M=4096, N=8192, K=2048 — BK=128, relu->int16
  gemm_i8_kernel<1, 128><<<dim3(HH / 128, MROWS / 128), 256, 0, stream>>>(
      xq, w1q, h16, nullptr, meanw, MROWS, HH, DD);
  quant_h_kernel<<<MROWS, 256, 0, stream>>>(h16, hq, a2, a1, meanw);
  // GEMM2: M=4096, N=2048, K=8192 — BK=256, scaled fp32
  gemm_i8_kernel<0, 256><<<dim3(DD / 128, MROWS / 128), 256, 0, stream>>>(
      hq, w2q, out, a2, &meanw[1], MROWS, DD, HH);
}